// Round 3
// baseline (2280.663 us; speedup 1.0000x reference)
//
#include <hip/hip_runtime.h>

// samx_qkv_1bit R14: break the loop-carried DS chain with one-step-ahead
// register prediction. R13 was flat: wall time = serial dependent-LDS chain
// (gather tk[cid] -> ballot -> readlane d -> load rec[d] -> bpermute ->
// permute -> gather), ~5 hops x ~130cyc with the gather at the back-edge and
// nothing independent to hide it.
// Key invariant: img[0] = tk[j_prev] = -1 ALWAYS (slot 0 is the fresh state;
// its transitions are only written by later steps' deferred stores). Hence
// t2==1 <=> img[1]!=-1, and img[1]=tk'[flj] is register-computable one step
// ahead: we hold post-step rec[flj] (clone we built / pb-patched rec[d] /
// register-tracked rec[0]). So:
//   - tail computes nx1 = tr[flj][ks']; if nx1 != -1 next step's
//     {t2=1, d=nx1, mlp=ml[flj], rec[d]=tail-prefetched} are register-known:
//     clone decision + early stores run with NO gather dependency, hiding
//     the gather latency under them.
//   - query: tail speculates tv0 = tr[w][qs'] and prefetches rec[tv0] +
//     rla[tv0]; the common zero-backoff walk1 then needs zero loads.
//   - previmg via DPP row_shr:1 (+3 readlane patches) replaces ds_bpermute.
//   - schedule: register front -> query -> gather-dep ballots/permute ->
//     deferred stores -> 4 batched independent tail prefetches.
// rec[0] is register-tracked (mutations: nobrk prefix tr[ks]=j; clone
// redirect run hitting root tr[ks]=bb; fallback reloads from LDS).
// Cold paths (chain > 64) keep the R10-verified serial fallback.

#define NSTATES 4096
#define TLEN 2048

typedef unsigned long long u64m;

__device__ __forceinline__ int f_tr(u64m r, int s) {   // transition by symbol
  return (int)(short)(unsigned short)(r >> (s << 4));
}
__device__ __forceinline__ int f_fl(u64m r) {          // suffix link
  return (int)(short)(unsigned short)(r >> 32);
}
__device__ __forceinline__ int f_ml(u64m r) {          // max length
  return (int)(r >> 48);
}
__device__ __forceinline__ u64m set_tr(u64m r, int s, int v) {
  const int sh = s << 4;
  return (r & ~(0xFFFFull << sh)) | ((u64m)(unsigned short)v << sh);
}

// img[lane-1] without DS: DPP row_shr:1 + patch row-boundary lanes 16/32/48.
// Lane 0 result is don't-care (rs requires lane >= t2 >= 1).
__device__ __forceinline__ int lane_shr1(int v, int lane) {
  int sh = __builtin_amdgcn_update_dpp(0, v, 0x111 /*row_shr:1*/, 0xF, 0xF, true);
  const int v15 = __builtin_amdgcn_readlane(v, 15);
  const int v31 = __builtin_amdgcn_readlane(v, 31);
  const int v47 = __builtin_amdgcn_readlane(v, 47);
  if (lane == 16) sh = v15;
  if (lane == 32) sh = v31;
  if (lane == 48) sh = v47;
  return sh;
}

__global__ __launch_bounds__(64)
void samx_main(const float* __restrict__ q,
               const float* __restrict__ k,
               unsigned* __restrict__ outpos,
               int T, int C) {
  __shared__ u64m           reca[NSTATES];  // tr0[15:0] tr1[31:16] fl[47:32] ml[63:48]
  __shared__ unsigned short rla[NSTATES];   // last end pos, 0xFFFF = -1

  unsigned short* recw = (unsigned short*)reca;  // [4*s + f]: f=0 tr0,1 tr1,2 fl,3 ml
  unsigned*       rech = (unsigned*)reca;        // [2*s+1] = fl|ml<<16

  const int row = blockIdx.x;
  const int b = row / C;
  const int c = row - b * C;
  const int lane = threadIdx.x;

  for (int s = lane; s < NSTATES; s += 64) {
    reca[s] = 0x0000FFFFFFFFFFFFull;  // tr0=tr1=fl=-1, ml=0
    rla[s] = 0xFFFFu;
  }

  const size_t rowbase = (size_t)b * (size_t)T * (size_t)C + (size_t)c;
  const float* qr = q + rowbase;
  const float* kr = k + rowbase;
  unsigned* outr = outpos + rowbase;

  // Pre-binarize: lane L holds bits t = 32L..32L+31 of q and k.
  unsigned qw = 0u, kw = 0u;
  {
    const int t0 = lane * 32;
#pragma unroll 8
    for (int jj = 0; jj < 32; ++jj) {
      const int t = t0 + jj;
      if (qr[(size_t)t * C] > 0.0f) qw |= (1u << jj);
      if (kr[(size_t)t * C] > 0.0f) kw |= (1u << jj);
    }
  }
  __syncthreads();

  int cid = 0;                  // my chain slot's state id (slot = lane)
  bool cval = (lane == 0);      // slot validity (valid slots contiguous)
  bool trunc = false;

  int g = 0;    // last state (uniform; used by fallback)
  int mlg = 0;  // ml[g]
  int u = 1;    // next free state id
  int w = 0;    // query-match state
  int h = 0;    // query-match length

  // ---- loop-carried prefetch/prediction state ----
  int qs = (int)(__builtin_amdgcn_readlane((int)qw, 0) & 1);
  int ks = (int)(__builtin_amdgcn_readlane((int)kw, 0) & 1);
  u64m pf_rec  = reca[0];              // rec[cid] gather
  u64m recp    = pf_rec;               // rec[w] for walk1 entry
  u64m rec0    = 0x0000FFFFFFFFFFFFull;  // register image of reca[0]
  u64m pf1c    = 0;                    // rec[flj] of previous step (uniform)
  u64m pf_recd = 0;                    // prefetched reca[nx1]
  u64m pf_recP = reca[0];              // speculated walk2-entry rec[tv0]
  int  pf_rlaP = (int)(short)rla[0];   // speculated rla[tv0]
  int  nx1     = -1;                   // predicted img[1] (t2==1 iff != -1)
  int  pf_tv0  = f_tr(recp, qs);       // speculated walk1 first transition

  for (int i = 0; i < T; ++i) {
    const bool hot = !trunc;

    const int j = u++;
    const int mlj = mlg + 1;

    int d = -1, bb = -1, flj = 0, ndd = 0, newlen = 2, pushed = 0, t2 = 64;
    bool nobrk = true, prefl = false, inrun = false, have_pf1 = false;
    u64m recd = 0, pf1n = 0;
    int img = -1, mlp = 0;

    if (hot) {
      // ---------- FRONT KEY (register-only in fast path) ----------
      if (nx1 >= 0) {
        // FAST: t2 == 1 guaranteed (img[0] == -1 invariant; img[1] = nx1)
        t2 = 1; nobrk = false; d = nx1; mlp = f_ml(pf1c); recd = pf_recd;
      } else {
        img = f_tr(pf_rec, ks);                   // gather-dependent
        const int myml = f_ml(pf_rec);
        const u64m brkmask = __ballot(cval && img != -1);
        nobrk = (brkmask == 0);
        t2 = nobrk ? 64 : (int)__builtin_ctzll(brkmask);
        const int t2c = (t2 > 63) ? 63 : t2;
        d = __builtin_amdgcn_readlane(img, t2c);
        mlp = __builtin_amdgcn_readlane(myml, t2c);
        recd = reca[d < 0 ? 0 : d];               // uniform-address b64
      }
      prefl = cval && (lane < t2);

      int dtr0 = f_tr(recd, 0), dtr1 = f_tr(recd, 1);
      {
        // patch deferred prefix-store effect on tk[d] (d may be a pre-t2 node)
        const u64m pb = __ballot(prefl && cid == d);
        if (pb != 0ull) { if (ks) dtr1 = j; else dtr0 = j; }
      }
      const unsigned fld = (unsigned)((recd >> 32) & 0xFFFFu);  // fl of d

      if (!nobrk) {
        const int mld = f_ml(recd);
        if (mlp + 1 == mld) {
          flj = d;
          pf1n = (u64m)(unsigned short)dtr0 | ((u64m)(unsigned short)dtr1 << 16)
               | ((u64m)fld << 32) | ((u64m)(unsigned)mld << 48);
        } else {
          bb = u++;  // clone of d with length mlp+1
          pf1n = (u64m)(unsigned short)dtr0 | ((u64m)(unsigned short)dtr1 << 16)
               | ((u64m)fld << 32) | ((u64m)(unsigned)(mlp + 1) << 48);
          // bb unreachable until deferred link stores land -> safe early.
          // rl[bb] copy elided: bb is slot 1 of the new chain -> stamped i.
          if (lane == 0) reca[bb] = pf1n;
          flj = bb;
        }
      }
      if (lane == 0)  // j likewise unreachable during the query
        rech[2 * j + 1] = (unsigned)(flj & 0xFFFF) | ((unsigned)mlj << 16);
      have_pf1 = true;  // nobrk: pf1n = rec0 assigned in deferred section
    }

    // ============ QUERY (wave-uniform; sees pre-key automaton) ============
    int p = w, x = h;
    u64m recP; int rlv;
    if (pf_tv0 != -1) {
      p = pf_tv0; x = h + 1;            // zero-backoff: everything prefetched
      recP = pf_recP; rlv = pf_rlaP;
    } else {
      u64m rr = recp;                   // tr[w][qs] == -1 known (pf_tv0 == -1)
      for (;;) {
        const int mp = f_ml(rr);
        if (x > mp) x = mp;
        p = f_fl(rr);
        if (p == -1) { p = 0; x = 0; break; }
        rr = reca[p];
        const int tv = f_tr(rr, qs);
        if (tv != -1) { p = tv; x = x + 1; break; }
      }
      recP = reca[p]; rlv = (int)(short)rla[p];
    }

    unsigned fmv = (unsigned)(recP >> 32);
    int vst = p;
    for (;;) {
      const int fv = (int)(short)(fmv & 0xFFFFu);
      if (fv == -1) break;
      const unsigned fmf = rech[2 * fv + 1];
      const int rlf = (int)(short)rla[fv];   // speculative, same hop
      if ((int)(fmf >> 16) < x) break;
      vst = fv; fmv = fmf; rlv = rlf;
    }
    int rv = -1;
    for (;;) {
      if (vst == -1) { rv = -1; break; }
      if ((int)(fmv >> 16) > 0 && rlv >= 0) { rv = rlv; break; }
      vst = (int)(short)(fmv & 0xFFFFu);
      if (vst == -1) { rv = -1; break; }
      fmv = rech[2 * vst + 1];
      rlv = (int)(short)rla[vst];
    }
    w = p; h = x;

    if (hot) {
      // -------- gather-dependent ballots + DEFERRED stores --------
      if (nx1 >= 0) img = f_tr(pf_rec, ks);   // first gather use in fast path

      if (prefl) recw[4 * cid + ks] = (unsigned short)j;
      if (bb >= 0) {  // redirect run: contiguous img==d from t2
        const u64m eq = __ballot(cval && img == d) >> t2;
        const int runlen = (eq == ~0ull) ? 64 : (int)__builtin_ctzll(~eq);
        inrun = cval && lane >= t2 && lane < t2 + runlen;
      }
      if (inrun) recw[4 * cid + ks] = (unsigned short)bb;
      if (bb >= 0 && lane == 0) recw[4 * d + 2] = (unsigned short)bb; // fl[d]=bb
      if (lane == 0) outr[(size_t)i * C] = (unsigned)(rv + 1);

      // next-iter query prefetch: patch recP with this step's stores.
      // rec[p] mutations: prefix j / redirect bb at cid==p, clone fl[d]=bb
      // at d==p (p < j so p is never a fresh state).
      u64m rp = recP;
      if (bb >= 0 && p == d)
        rp = (rp & ~(0xFFFFull << 32)) | ((u64m)(unsigned short)bb << 32);
      if (__ballot(prefl && cid == p) != 0ull) rp = set_tr(rp, ks, j);
      if (__ballot(inrun && cid == p) != 0ull) rp = set_tr(rp, ks, bb);
      recp = rp;

      // rec0 register maintenance (root mutations: nobrk prefix store;
      // clone redirect run reaching the root slot)
      if (nobrk) rec0 = set_tr(rec0, ks, j);
      else if (bb >= 0 && __ballot(inrun && cid == 0) != 0ull)
        rec0 = set_tr(rec0, ks, bb);
      if (nobrk) pf1n = rec0;   // flj == 0 (root)

      // dedup run-starts from PRE-redirect img (identical post-redirect)
      const int previmg = lane_shr1(img, lane);
      const bool rs = cval && lane >= t2 && (lane == t2 || img != previmg);
      const u64m rsmask = __ballot(rs);
      ndd = (int)__builtin_popcountll(rsmask);
      newlen = ndd + 2;  // [j] + ndd images + [root]
      const unsigned below =
          __builtin_amdgcn_mbcnt_hi((unsigned)(rsmask >> 32),
              __builtin_amdgcn_mbcnt_lo((unsigned)rsmask, 0u));
      // run-start #q pushes its image to slot q+1; others push to trash
      // slot 0 (only lane 0 reads it; lane 0 overrides with j; slot 1
      // overridden with flj, absorbing the redirect patch).
      const int dst = rs ? ((int)below + 1) : 0;
      pushed = __builtin_amdgcn_ds_permute(dst << 2, img);

      // new chain: [j, flj, run-start images #1.., root]
      int nv = 0;  // default root/padding (safe gather next step)
      if (lane == 0) nv = j;
      else if (lane == 1) nv = flj;
      else if (lane - 1 < ndd) nv = pushed;
      const bool nval = (lane < newlen);
      if (nval) rla[nv] = (unsigned short)i;   // after query's rla reads

      const bool overflow = (newlen > 64);
      if (overflow) {  // cold: stamp the unstored tail serially
        const int nv63 = __builtin_amdgcn_readlane(nv, 63);
        if (lane == 0) {
          int vp = (int)(short)(rech[2 * nv63 + 1] & 0xFFFFu);
          while (vp != -1) {
            rla[vp] = (unsigned short)i;
            vp = (int)(short)(rech[2 * vp + 1] & 0xFFFFu);
          }
        }
        have_pf1 = false;
      }
      cid = nv; cval = nval; trunc = overflow;
    } else {
      // ======= COLD fallback: reference-exact serial step (R10-verified) ====
      int pcur = g, d2 = -1, idbrk = -1;
      for (;;) {
        if (pcur == -1) break;
        const u64m rr = reca[pcur];
        const int tv = f_tr(rr, ks);
        if (tv != -1) { d2 = tv; idbrk = pcur; break; }
        if (lane == 0) recw[4 * pcur + ks] = (unsigned short)j;
        pcur = f_fl(rr);
      }
      int fl2 = 0;
      if (d2 != -1) {
        const int mlp2 = f_ml(reca[idbrk]);
        const u64m rd2 = reca[d2];
        const int mld = f_ml(rd2);
        if (mlp2 + 1 == mld) {
          fl2 = d2;
        } else {
          const int bbc = u++;
          const int drl = (int)(short)rla[d2];
          if (lane == 0) {
            reca[bbc] = (u64m)(unsigned short)f_tr(rd2, 0)
                      | ((u64m)(unsigned short)f_tr(rd2, 1) << 16)
                      | ((u64m)((unsigned)(rd2 >> 32) & 0xFFFFu) << 32)
                      | ((u64m)(unsigned)(mlp2 + 1) << 48);
            rla[bbc] = (unsigned short)drl;
            recw[4 * d2 + 2] = (unsigned short)bbc;   // fl[d2] = bbc
          }
          fl2 = bbc;
          int p3 = idbrk;
          for (;;) {
            if (p3 == -1) break;
            const u64m r3 = reca[p3];
            const int tv3 = f_tr(r3, ks);
            if (tv3 != d2) break;
            if (lane == 0) recw[4 * p3 + ks] = (unsigned short)bbc;
            p3 = f_fl(r3);
          }
        }
      }
      if (lane == 0) {
        rech[2 * j + 1] = (unsigned)(fl2 & 0xFFFF) | ((unsigned)mlj << 16);
        outr[(size_t)i * C] = (unsigned)(rv + 1);
      }
      // full propagation walk; rebuild lane chain while stamping
      int vp = j, ncs = 0;
      bool tr2 = false;
      for (;;) {
        if (vp == -1) break;
        if (ncs < 64) { if (lane == ncs) cid = vp; ++ncs; }
        else tr2 = true;
        if (lane == 0) rla[vp] = (unsigned short)i;
        vp = (int)(short)(rech[2 * vp + 1] & 0xFFFFu);
      }
      cval = (lane < ncs);
      trunc = tr2;
      recp = reca[w];   // fresh (post-stores) query prefetch
      rec0 = reca[0];   // resync register image of root
      have_pf1 = false;
    }
    g = j; mlg = mlj;

    // ---- tail prefetches for i+1: 4 independent pipelined DS loads, all
    // issued after every store of this step (in-order DS => coherent; step
    // i+1's early stores touch only fresh j'/bb' > all prefetched states) ----
    if (i + 1 < T) {
      pf_rec = reca[cid];                               // chain gather
      const int in = i + 1;
      const unsigned qwn = (unsigned)__builtin_amdgcn_readlane((int)qw, in >> 5);
      const unsigned kwn = (unsigned)__builtin_amdgcn_readlane((int)kw, in >> 5);
      qs = (int)((qwn >> (in & 31)) & 1u);
      ks = (int)((kwn >> (in & 31)) & 1u);
      pf_tv0 = f_tr(recp, qs);                          // walk1 speculation
      const int pa = pf_tv0 < 0 ? 0 : pf_tv0;
      pf_recP = reca[pa];
      pf_rlaP = (int)(short)rla[pa];
      nx1 = have_pf1 ? f_tr(pf1n, ks) : -1;             // t2==1 prediction
      const int da = nx1 < 0 ? 0 : nx1;
      pf_recd = reca[da];
      pf1c = pf1n;
    }
  }
}

// Fully parallel epilogue: vidx (u32, = r+1, 0 = no match) -> sign*e.
__global__ __launch_bounds__(256)
void samx_epilogue(const float* __restrict__ v,
                   const float* __restrict__ e,
                   unsigned* __restrict__ out,
                   int T, int C, int total) {
  const int idx = blockIdx.x * 256 + threadIdx.x;
  if (idx >= total) return;
  const unsigned vidx = out[idx];
  const int c = idx % C;
  const int bi = idx / C;
  const int b = bi / T;
  const float ev = e[c];
  float val = -ev;  // y=0
  if (vidx != 0u) {
    if (v[((size_t)b * (size_t)T + (size_t)vidx) * (size_t)C + (size_t)c] > 0.0f)
      val = ev;
  }
  out[idx] = __float_as_uint(val);
}

extern "C" void kernel_launch(void* const* d_in, const int* in_sizes, int n_in,
                              void* d_out, int out_size, void* d_ws, size_t ws_size,
                              hipStream_t stream) {
  const float* q = (const float*)d_in[0];
  const float* k = (const float*)d_in[1];
  const float* v = (const float*)d_in[2];
  const float* e = (const float*)d_in[3];

  const int C = in_sizes[3];
  const int T = TLEN;
  const int B = in_sizes[0] / (T * C);
  const int total = out_size;

  samx_main<<<dim3(B * C), dim3(64), 0, stream>>>(q, k, (unsigned*)d_out, T, C);
  samx_epilogue<<<dim3((total + 255) / 256), dim3(256), 0, stream>>>(
      v, e, (unsigned*)d_out, T, C, total);
}

// Round 4
// 1941.117 us; speedup vs baseline: 1.1749x; 1.1749x over previous
//
#include <hip/hip_runtime.h>

// samx_qkv_1bit R15: R13 base + two surgical back-edge cuts.
// R14 post-mortem: moving the previmg/rs/permute cluster AFTER the query
// (plus 3 extra tail prefetches) put 2 DS-hop latencies on the loop-carried
// cycle -> +300us. Reverted to R13's schedule (permute issued in the EARLY
// key block, overlapping the query walk; single tail gather).
// R15 changes vs R13 (both verified correct by R14's passing run):
//   1. previmg via DPP row_shr:1 + 3 readlane patches (VALU-only) replaces
//      ds_bpermute: removes one dependent DS hop from the img -> rs ->
//      permute issue path.
//   2. permute machinery (previmg/rs/rsmask/dst/ds_permute) hoisted ABOVE
//      the recd-dependent clone block: rs depends only on img, so the
//      permute now issues ~one load-latency earlier; its result (nv) is
//      long returned by the post-query consumers.
// Everything else identical to R13: packed u64 rec[] (one b64 per hop),
// speculative rla co-loads, rec[p]-reuse prefetch with register patching,
// R10-verified cold fallback.

#define NSTATES 4096
#define TLEN 2048

typedef unsigned long long u64m;

__device__ __forceinline__ int f_tr(u64m r, int s) {   // transition by symbol
  return (int)(short)(unsigned short)(r >> (s << 4));
}
__device__ __forceinline__ int f_fl(u64m r) {          // suffix link
  return (int)(short)(unsigned short)(r >> 32);
}
__device__ __forceinline__ int f_ml(u64m r) {          // max length
  return (int)(r >> 48);
}
__device__ __forceinline__ u64m set_tr(u64m r, int s, int v) {
  const int sh = s << 4;
  return (r & ~(0xFFFFull << sh)) | ((u64m)(unsigned short)v << sh);
}

// img[lane-1] without DS: DPP row_shr:1 + patch row-boundary lanes 16/32/48.
// Lane 0 result is don't-care (rs requires lane >= t2 >= 1).
__device__ __forceinline__ int lane_shr1(int v, int lane) {
  int sh = __builtin_amdgcn_update_dpp(0, v, 0x111 /*row_shr:1*/, 0xF, 0xF, true);
  const int v15 = __builtin_amdgcn_readlane(v, 15);
  const int v31 = __builtin_amdgcn_readlane(v, 31);
  const int v47 = __builtin_amdgcn_readlane(v, 47);
  if (lane == 16) sh = v15;
  if (lane == 32) sh = v31;
  if (lane == 48) sh = v47;
  return sh;
}

__global__ __launch_bounds__(64)
void samx_main(const float* __restrict__ q,
               const float* __restrict__ k,
               unsigned* __restrict__ outpos,
               int T, int C) {
  __shared__ u64m           reca[NSTATES];  // tr0[15:0] tr1[31:16] fl[47:32] ml[63:48]
  __shared__ unsigned short rla[NSTATES];   // last end pos, 0xFFFF = -1

  unsigned short* recw = (unsigned short*)reca;  // [4*s + f]: f=0 tr0,1 tr1,2 fl,3 ml
  unsigned*       rech = (unsigned*)reca;        // [2*s+1] = fl|ml<<16

  const int row = blockIdx.x;
  const int b = row / C;
  const int c = row - b * C;
  const int lane = threadIdx.x;

  for (int s = lane; s < NSTATES; s += 64) {
    reca[s] = 0x0000FFFFFFFFFFFFull;  // tr0=tr1=fl=-1, ml=0
    rla[s] = 0xFFFFu;
  }

  const size_t rowbase = (size_t)b * (size_t)T * (size_t)C + (size_t)c;
  const float* qr = q + rowbase;
  const float* kr = k + rowbase;
  unsigned* outr = outpos + rowbase;

  // Pre-binarize: lane L holds bits t = 32L..32L+31 of q and k.
  unsigned qw = 0u, kw = 0u;
  {
    const int t0 = lane * 32;
#pragma unroll 8
    for (int jj = 0; jj < 32; ++jj) {
      const int t = t0 + jj;
      if (qr[(size_t)t * C] > 0.0f) qw |= (1u << jj);
      if (kr[(size_t)t * C] > 0.0f) kw |= (1u << jj);
    }
  }
  __syncthreads();

  int cid = 0;                  // my chain slot's state id (slot = lane)
  bool cval = (lane == 0);      // slot validity (valid slots contiguous)
  bool trunc = false;

  int g = 0;    // last state (uniform; used by fallback)
  int mlg = 0;  // ml[g]
  int u = 1;    // next free state id
  int w = 0;    // query-match state
  int h = 0;    // query-match length

  // ---- prologue prefetch for i = 0 ----
  int qs = (int)(__builtin_amdgcn_readlane((int)qw, 0) & 1);
  int ks = (int)(__builtin_amdgcn_readlane((int)kw, 0) & 1);
  u64m pf_rec = reca[0];   // rec[cid] (all cids are 0)
  u64m recp   = pf_rec;    // rec[w]   (w = 0)

  for (int i = 0; i < T; ++i) {
    const bool hot = !trunc;
    const u64m rk  = pf_rec;          // rec[cid], pre-key value (prefetched)
    const int img  = f_tr(rk, ks);
    const int myml = f_ml(rk);

    const int j = u++;
    const int mlj = mlg + 1;

    // persists early -> deferred
    int d = -1, bb = -1, flj = 0, ndd = 0, newlen = 2, pushed = 0;
    bool prefl = false, inrun = false;

    if (hot) {
      // ---------- EARLY KEY: everything not visible to the query ----------
      const u64m brkmask = __ballot(cval && img != -1);
      const bool nobrk = (brkmask == 0);
      const int t2 = nobrk ? 64 : (int)__builtin_ctzll(brkmask);
      const int t2c = (t2 > 63) ? 63 : t2;
      d = __builtin_amdgcn_readlane(img, t2c);   // uniform idx -> no DS hop
      const int mlp = __builtin_amdgcn_readlane(myml, t2c);
      const int dld = (d < 0) ? 0 : d;
      prefl = cval && (lane < t2);

      // ONE b64: tr0,tr1,fl,ml of d (issue now; consumed by clone block)
      const u64m recd = reca[dld];

      // ---- permute machinery: depends only on img -> issue permute ASAP
      // (overlaps both the recd load and the whole query walk) ----
      const int previmg = lane_shr1(img, lane);   // VALU-only (was bpermute)
      // run-start mask from PRE-redirect img (identical post-redirect: the
      // redirect swaps a maximal run of d for an equal-length run of bb)
      const bool rs = cval && lane >= t2 && (lane == t2 || img != previmg);
      const u64m rsmask = __ballot(rs);
      ndd = (int)__builtin_popcountll(rsmask);
      newlen = ndd + 2;  // [j] + ndd images + [root]
      const unsigned below =
          __builtin_amdgcn_mbcnt_hi((unsigned)(rsmask >> 32),
              __builtin_amdgcn_mbcnt_lo((unsigned)rsmask, 0u));
      // run-start #q pushes its image to slot q+1; others push to trash
      // slot 0 (only lane 0 reads it, and lane 0 overrides with j; slot 1
      // is overridden with flj, absorbing the redirect patch).
      const int dst = rs ? ((int)below + 1) : 0;
      pushed = __builtin_amdgcn_ds_permute(dst << 2, img);

      // ---- clone decision (recd-dependent) ----
      int dtr0 = f_tr(recd, 0);
      int dtr1 = f_tr(recd, 1);
      const unsigned fmdhi = (unsigned)(recd >> 32);  // fl|ml of d
      if (!nobrk) {
        const int mld = (int)(fmdhi >> 16);
        if (mlp + 1 == mld) {
          flj = d;
        } else {
          bb = u++;  // clone of d with length mlp+1
          // register patch of the deferred prefix stores' effect on tk[d]
          const u64m pb = __ballot(prefl && cid == d);
          if (pb != 0ull) { if (ks) dtr1 = j; else dtr0 = j; }
          if (lane == 0) {
            // bb unreachable until deferred link stores land -> safe early
            // rl[bb] copy elided: bb is slot 1 of the new chain -> stamped i
            reca[bb] = (u64m)(unsigned short)dtr0
                     | ((u64m)(unsigned short)dtr1 << 16)
                     | ((u64m)(fmdhi & 0xFFFFu) << 32)
                     | ((u64m)(unsigned)(mlp + 1) << 48);
          }
          flj = bb;
        }
      }
      if (lane == 0)  // j likewise unreachable during the query
        rech[2 * j + 1] = (unsigned)(flj & 0xFFFF) | ((unsigned)mlj << 16);

      // redirect run (clone only): contiguous img==d from t2
      if (bb >= 0) {
        const u64m eq = __ballot(cval && img == d) >> t2;
        const int runlen = (eq == ~0ull) ? 64 : (int)__builtin_ctzll(~eq);
        inrun = cval && lane >= t2 && lane < t2 + runlen;
      }
    }

    // ============ QUERY (wave-uniform; sees pre-key automaton) ============
    int p = w, x = h;
    {
      u64m rr = recp;  // prefetched rec[w] (patched for last step's stores)
      for (;;) {
        if (p == -1) { p = 0; x = 0; break; }
        const int tv = f_tr(rr, qs);
        if (tv != -1) { p = tv; x = x + 1; break; }
        const int mp = f_ml(rr);
        if (x > mp) x = mp;
        p = f_fl(rr);
        if (p == -1) { p = 0; x = 0; break; }
        rr = reca[p];   // ONE b64 per hop
      }
    }

    // walk2 entry: rec[p] (also next step's query prefetch) + speculative rla
    const u64m recP = reca[p];
    int rlv = (int)(short)rla[p];
    unsigned fmv = (unsigned)(recP >> 32);
    int vst = p;
    for (;;) {
      const int fv = (int)(short)(fmv & 0xFFFFu);
      if (fv == -1) break;
      const unsigned fmf = rech[2 * fv + 1];
      const int rlf = (int)(short)rla[fv];   // speculative, same hop
      if ((int)(fmf >> 16) < x) break;
      vst = fv; fmv = fmf; rlv = rlf;
    }
    int rv = -1;
    for (;;) {
      if (vst == -1) { rv = -1; break; }
      if ((int)(fmv >> 16) > 0 && rlv >= 0) { rv = rlv; break; }  // entry free
      vst = (int)(short)(fmv & 0xFFFFu);
      if (vst == -1) { rv = -1; break; }
      fmv = rech[2 * vst + 1];
      rlv = (int)(short)rla[vst];
    }
    w = p; h = x;

    if (hot) {
      // -------- DEFERRED KEY: stores the query must not observe --------
      if (prefl) recw[4 * cid + ks] = (unsigned short)j;
      if (inrun) recw[4 * cid + ks] = (unsigned short)bb;
      if (bb >= 0 && lane == 0) recw[4 * d + 2] = (unsigned short)bb;  // fl[d]=bb
      if (lane == 0) outr[(size_t)i * C] = (unsigned)(rv + 1);

      // next-iter query prefetch: patch recP with this step's stores.
      // rec[p] mutations are exactly {prefix j, redirect bb} at cid==p and
      // clone fl[d]=bb at d==p (p != j,bb: p predates this step).
      u64m rp = recP;
      if (bb >= 0 && p == d)
        rp = (rp & ~(0xFFFFull << 32)) | ((u64m)(unsigned short)bb << 32);
      if (__ballot(prefl && cid == p) != 0ull) rp = set_tr(rp, ks, j);
      if (__ballot(inrun && cid == p) != 0ull) rp = set_tr(rp, ks, bb);
      recp = rp;

      // new chain: [j, flj, run-start images #1.., root]
      int nv = 0;  // default root/padding (safe gather next step)
      if (lane == 0) nv = j;
      else if (lane == 1) nv = flj;
      else if (lane - 1 < ndd) nv = pushed;   // permute long returned by now
      const bool nval = (lane < newlen);
      if (nval) rla[nv] = (unsigned short)i;   // after query's rla reads

      const bool overflow = (newlen > 64);
      if (overflow) {  // cold: stamp the unstored tail serially
        const int nv63 = __builtin_amdgcn_readlane(nv, 63);
        if (lane == 0) {
          int vp = (int)(short)(rech[2 * nv63 + 1] & 0xFFFFu);
          while (vp != -1) {
            rla[vp] = (unsigned short)i;
            vp = (int)(short)(rech[2 * vp + 1] & 0xFFFFu);
          }
        }
      }
      cid = nv; cval = nval; trunc = overflow;
    } else {
      // ======= COLD fallback: reference-exact serial step (R10-verified) ====
      int pcur = g, d2 = -1, idbrk = -1;
      for (;;) {
        if (pcur == -1) break;
        const u64m rr = reca[pcur];
        const int tv = f_tr(rr, ks);
        if (tv != -1) { d2 = tv; idbrk = pcur; break; }
        if (lane == 0) recw[4 * pcur + ks] = (unsigned short)j;
        pcur = f_fl(rr);
      }
      int fl2 = 0;
      if (d2 != -1) {
        const int mlp2 = f_ml(reca[idbrk]);
        const u64m rd2 = reca[d2];
        const int mld = f_ml(rd2);
        if (mlp2 + 1 == mld) {
          fl2 = d2;
        } else {
          const int bbc = u++;
          const int drl = (int)(short)rla[d2];
          if (lane == 0) {
            reca[bbc] = (u64m)(unsigned short)f_tr(rd2, 0)
                      | ((u64m)(unsigned short)f_tr(rd2, 1) << 16)
                      | ((u64m)((unsigned)(rd2 >> 32) & 0xFFFFu) << 32)
                      | ((u64m)(unsigned)(mlp2 + 1) << 48);
            rla[bbc] = (unsigned short)drl;
            recw[4 * d2 + 2] = (unsigned short)bbc;   // fl[d2] = bbc
          }
          fl2 = bbc;
          int p3 = idbrk;
          for (;;) {
            if (p3 == -1) break;
            const u64m r3 = reca[p3];
            const int tv3 = f_tr(r3, ks);
            if (tv3 != d2) break;
            if (lane == 0) recw[4 * p3 + ks] = (unsigned short)bbc;
            p3 = f_fl(r3);
          }
        }
      }
      if (lane == 0) {
        rech[2 * j + 1] = (unsigned)(fl2 & 0xFFFF) | ((unsigned)mlj << 16);
        outr[(size_t)i * C] = (unsigned)(rv + 1);
      }
      // full propagation walk; rebuild lane chain while stamping
      int vp = j, ncs = 0;
      bool tr2 = false;
      for (;;) {
        if (vp == -1) break;
        if (ncs < 64) { if (lane == ncs) cid = vp; ++ncs; }
        else tr2 = true;
        if (lane == 0) rla[vp] = (unsigned short)i;
        vp = (int)(short)(rech[2 * vp + 1] & 0xFFFFu);
      }
      cval = (lane < ncs);
      trunc = tr2;
      recp = reca[w];   // fresh (post-stores) query prefetch
    }
    g = j; mlg = mlj;

    // ---- tail prefetch for i+1: ONE per-lane gather (in-order DS => sees
    // every store of this step; next step's early stores touch only fresh
    // j'/bb' != cid) ----
    if (i + 1 < T) {
      pf_rec = reca[cid];
      const int in = i + 1;
      const unsigned qwn = (unsigned)__builtin_amdgcn_readlane((int)qw, in >> 5);
      const unsigned kwn = (unsigned)__builtin_amdgcn_readlane((int)kw, in >> 5);
      qs = (int)((qwn >> (in & 31)) & 1u);
      ks = (int)((kwn >> (in & 31)) & 1u);
    }
  }
}

// Fully parallel epilogue: vidx (u32, = r+1, 0 = no match) -> sign*e.
__global__ __launch_bounds__(256)
void samx_epilogue(const float* __restrict__ v,
                   const float* __restrict__ e,
                   unsigned* __restrict__ out,
                   int T, int C, int total) {
  const int idx = blockIdx.x * 256 + threadIdx.x;
  if (idx >= total) return;
  const unsigned vidx = out[idx];
  const int c = idx % C;
  const int bi = idx / C;
  const int b = bi / T;
  const float ev = e[c];
  float val = -ev;  // y=0
  if (vidx != 0u) {
    if (v[((size_t)b * (size_t)T + (size_t)vidx) * (size_t)C + (size_t)c] > 0.0f)
      val = ev;
  }
  out[idx] = __float_as_uint(val);
}

extern "C" void kernel_launch(void* const* d_in, const int* in_sizes, int n_in,
                              void* d_out, int out_size, void* d_ws, size_t ws_size,
                              hipStream_t stream) {
  const float* q = (const float*)d_in[0];
  const float* k = (const float*)d_in[1];
  const float* v = (const float*)d_in[2];
  const float* e = (const float*)d_in[3];

  const int C = in_sizes[3];
  const int T = TLEN;
  const int B = in_sizes[0] / (T * C);
  const int total = out_size;

  samx_main<<<dim3(B * C), dim3(64), 0, stream>>>(q, k, (unsigned*)d_out, T, C);
  samx_epilogue<<<dim3((total + 255) / 256), dim3(256), 0, stream>>>(
      v, e, (unsigned*)d_out, T, C, total);
}

// Round 5
// 1577.222 us; speedup vs baseline: 1.4460x; 1.2307x over previous
//
#include <hip/hip_runtime.h>

// samx_qkv_1bit R16: two-wave split — key-wave ∥ query-wave.
// R15 plateau diagnosis: 1024 rows x 40KB LDS = the chip's entire 40MB LDS
// -> 1 wave/SIMD, and program order forces key-chain + query-chain stalls
// to be paid serially (~2200 cyc/step) even though they are independent
// (query@i reads only the post-(i-1) automaton; R12-verified discipline).
// R16: 128-thread blocks. Wave0 = key side, wave1 = query side. Same 40KB
// -> still 4 blocks/CU but 8 waves/CU (2/SIMD); per-step wall becomes
// max(key, query) + 2 barriers instead of key + query.
//   Phase1 (B->A): wave0 key READS + stores to fresh j/bb (unreachable by
//     query until phase2 links them); wave1 full query (walk1/2/3) + outr.
//     Wave1 never writes LDS -> phase1 is race-free by construction.
//   Phase2 (A->B): wave0 alone: query-visible stores (prefix/redirect tk,
//     fl[d]=bb, rla stamps; cold fallback runs entirely here), then
//     s_waitcnt lgkmcnt(0) before a RAW s_barrier (no __syncthreads: avoids
//     draining wave1's in-flight outr global store every step).
// recp register-patch machinery deleted: wave1 reloads rec[w] fresh each
// step (hidden under wave0's concurrent chain). Cold fallback R10-verified,
// verbatim in wave0's exclusive phase. Permute/lane_shr1/packed-rec as R15.

#define NSTATES 4096
#define TLEN 2048

typedef unsigned long long u64m;

__device__ __forceinline__ int f_tr(u64m r, int s) {   // transition by symbol
  return (int)(short)(unsigned short)(r >> (s << 4));
}
__device__ __forceinline__ int f_fl(u64m r) {          // suffix link
  return (int)(short)(unsigned short)(r >> 32);
}
__device__ __forceinline__ int f_ml(u64m r) {          // max length
  return (int)(r >> 48);
}

// img[lane-1] without DS: DPP row_shr:1 + patch row-boundary lanes 16/32/48.
// Lane 0 result is don't-care (rs requires lane >= t2 >= 1).
__device__ __forceinline__ int lane_shr1(int v, int lane) {
  int sh = __builtin_amdgcn_update_dpp(0, v, 0x111 /*row_shr:1*/, 0xF, 0xF, true);
  const int v15 = __builtin_amdgcn_readlane(v, 15);
  const int v31 = __builtin_amdgcn_readlane(v, 31);
  const int v47 = __builtin_amdgcn_readlane(v, 47);
  if (lane == 16) sh = v15;
  if (lane == 32) sh = v31;
  if (lane == 48) sh = v47;
  return sh;
}

__global__ __launch_bounds__(128)
void samx_main(const float* __restrict__ q,
               const float* __restrict__ k,
               unsigned* __restrict__ outpos,
               int T, int C) {
  __shared__ u64m           reca[NSTATES];  // tr0[15:0] tr1[31:16] fl[47:32] ml[63:48]
  __shared__ unsigned short rla[NSTATES];   // last end pos, 0xFFFF = -1

  unsigned short* recw = (unsigned short*)reca;  // [4*s + f]: f=0 tr0,1 tr1,2 fl,3 ml
  unsigned*       rech = (unsigned*)reca;        // [2*s+1] = fl|ml<<16

  const int row = blockIdx.x;
  const int b = row / C;
  const int c = row - b * C;
  const int lane = threadIdx.x & 63;
  const int wid = threadIdx.x >> 6;   // 0 = key wave, 1 = query wave

  for (int s = threadIdx.x; s < NSTATES; s += 128) {
    reca[s] = 0x0000FFFFFFFFFFFFull;  // tr0=tr1=fl=-1, ml=0
    rla[s] = 0xFFFFu;
  }

  const size_t rowbase = (size_t)b * (size_t)T * (size_t)C + (size_t)c;
  unsigned* outr = outpos + rowbase;

  // Binarize only the stream this wave consumes: wave0 -> k, wave1 -> q.
  // Lane L holds bits t = 32L..32L+31.
  const float* src = (wid == 0 ? k : q) + rowbase;
  unsigned bits = 0u;
  {
    const int t0 = lane * 32;
#pragma unroll 8
    for (int jj = 0; jj < 32; ++jj) {
      if (src[(size_t)(t0 + jj) * C] > 0.0f) bits |= (1u << jj);
    }
  }
  __syncthreads();

  // ---- wave0 state ----
  int cid = 0;                  // my chain slot's state id (slot = lane)
  bool cval = (lane == 0);      // slot validity (valid slots contiguous)
  bool trunc = false;
  int g = 0;    // last state (uniform; used by fallback)
  int mlg = 0;  // ml[g]
  int u = 1;    // next free state id
  // ---- wave1 state ----
  int w = 0;    // query-match state
  int h = 0;    // query-match length

  int sym = (int)(__builtin_amdgcn_readlane((int)bits, 0) & 1);  // ks / qs

  for (int i = 0; i < T; ++i) {
    const bool hot = !trunc;
    const int j = u++;          // wave1's copies of u/j are unused
    const int mlj = mlg + 1;

    // phase1 -> phase2 carriers (wave0)
    int d = -1, bb = -1, flj = 0, ndd = 0, newlen = 2, pushed = 0;
    bool prefl = false, inrun = false;

    if (wid == 0) {
      // ================= PHASE 1 — KEY (reads + fresh stores) =============
      if (hot) {
        const int ks = sym;
        const u64m rk = reca[cid];                 // gather (post-(i-1))
        const int img = f_tr(rk, ks);
        const int myml = f_ml(rk);
        const u64m brkmask = __ballot(cval && img != -1);
        const bool nobrk = (brkmask == 0);
        const int t2 = nobrk ? 64 : (int)__builtin_ctzll(brkmask);
        const int t2c = (t2 > 63) ? 63 : t2;
        d = __builtin_amdgcn_readlane(img, t2c);
        const int mlp = __builtin_amdgcn_readlane(myml, t2c);
        prefl = cval && (lane < t2);

        const u64m recd = reca[d < 0 ? 0 : d];     // ONE b64 for d

        // permute machinery (img-only; overlaps recd load)
        const int previmg = lane_shr1(img, lane);
        const bool rs = cval && lane >= t2 && (lane == t2 || img != previmg);
        const u64m rsmask = __ballot(rs);
        ndd = (int)__builtin_popcountll(rsmask);
        newlen = ndd + 2;  // [j] + ndd images + [root]
        const unsigned below =
            __builtin_amdgcn_mbcnt_hi((unsigned)(rsmask >> 32),
                __builtin_amdgcn_mbcnt_lo((unsigned)rsmask, 0u));
        const int dst = rs ? ((int)below + 1) : 0; // trash -> slot 0
        pushed = __builtin_amdgcn_ds_permute(dst << 2, img);

        // clone decision + fresh-state stores (invisible to wave1: nothing
        // links to j/bb until phase2)
        int dtr0 = f_tr(recd, 0);
        int dtr1 = f_tr(recd, 1);
        const unsigned fmdhi = (unsigned)(recd >> 32);  // fl|ml of d
        if (!nobrk) {
          const int mld = (int)(fmdhi >> 16);
          if (mlp + 1 == mld) {
            flj = d;
          } else {
            bb = u++;  // clone of d with length mlp+1
            // patch phase2 prefix-store effect on tk[d] (d may be pre-t2 node)
            const u64m pb = __ballot(prefl && cid == d);
            if (pb != 0ull) { if (ks) dtr1 = j; else dtr0 = j; }
            if (lane == 0) {
              // rl[bb] copy elided: bb is slot 1 of new chain -> stamped i
              reca[bb] = (u64m)(unsigned short)dtr0
                       | ((u64m)(unsigned short)dtr1 << 16)
                       | ((u64m)(fmdhi & 0xFFFFu) << 32)
                       | ((u64m)(unsigned)(mlp + 1) << 48);
            }
            flj = bb;
          }
        }
        if (lane == 0)
          rech[2 * j + 1] = (unsigned)(flj & 0xFFFF) | ((unsigned)mlj << 16);

        if (bb >= 0) {  // redirect run: contiguous img==d from t2
          const u64m eq = __ballot(cval && img == d) >> t2;
          const int runlen = (eq == ~0ull) ? 64 : (int)__builtin_ctzll(~eq);
          inrun = cval && lane >= t2 && lane < t2 + runlen;
        }
      }
    } else {
      // ================= PHASE 1 — QUERY (reads only; sees post-(i-1)) ====
      const int qs = sym;
      int p = w, x = h;
      {
        u64m rr = reca[w];
        for (;;) {
          const int tv = f_tr(rr, qs);
          if (tv != -1) { p = tv; x = x + 1; break; }
          const int mp = f_ml(rr);
          if (x > mp) x = mp;
          p = f_fl(rr);
          if (p == -1) { p = 0; x = 0; break; }
          rr = reca[p];   // ONE b64 per hop
        }
      }
      const u64m recP = reca[p];
      int rlv = (int)(short)rla[p];
      unsigned fmv = (unsigned)(recP >> 32);
      int vst = p;
      for (;;) {
        const int fv = (int)(short)(fmv & 0xFFFFu);
        if (fv == -1) break;
        const unsigned fmf = rech[2 * fv + 1];
        const int rlf = (int)(short)rla[fv];   // speculative, same hop
        if ((int)(fmf >> 16) < x) break;
        vst = fv; fmv = fmf; rlv = rlf;
      }
      int rv = -1;
      for (;;) {
        if (vst == -1) { rv = -1; break; }
        if ((int)(fmv >> 16) > 0 && rlv >= 0) { rv = rlv; break; }
        vst = (int)(short)(fmv & 0xFFFFu);
        if (vst == -1) { rv = -1; break; }
        fmv = rech[2 * vst + 1];
        rlv = (int)(short)rla[vst];
      }
      w = p; h = x;
      if (lane == 0) outr[(size_t)i * C] = (unsigned)(rv + 1);
    }

    asm volatile("" ::: "memory");
    __builtin_amdgcn_s_barrier();   // ---- A: query reads done ----
    asm volatile("" ::: "memory");

    if (wid == 0) {
      // ============ PHASE 2 — KEY visible stores (exclusive) ==============
      const int ks = sym;
      if (hot) {
        if (prefl) recw[4 * cid + ks] = (unsigned short)j;
        if (inrun) recw[4 * cid + ks] = (unsigned short)bb;
        if (bb >= 0 && lane == 0) recw[4 * d + 2] = (unsigned short)bb; // fl[d]=bb

        // new chain: [j, flj, run-start images #1.., root]
        int nv = 0;  // default root/padding (safe gather next step)
        if (lane == 0) nv = j;
        else if (lane == 1) nv = flj;
        else if (lane - 1 < ndd) nv = pushed;
        const bool nval = (lane < newlen);
        if (nval) rla[nv] = (unsigned short)i;

        const bool overflow = (newlen > 64);
        if (overflow) {  // cold: stamp the unstored tail serially
          const int nv63 = __builtin_amdgcn_readlane(nv, 63);
          if (lane == 0) {
            int vp = (int)(short)(rech[2 * nv63 + 1] & 0xFFFFu);
            while (vp != -1) {
              rla[vp] = (unsigned short)i;
              vp = (int)(short)(rech[2 * vp + 1] & 0xFFFFu);
            }
          }
        }
        cid = nv; cval = nval; trunc = overflow;
      } else {
        // ===== COLD fallback: reference-exact serial step (R10-verified) ==
        int pcur = g, d2 = -1, idbrk = -1;
        for (;;) {
          if (pcur == -1) break;
          const u64m rr = reca[pcur];
          const int tv = f_tr(rr, ks);
          if (tv != -1) { d2 = tv; idbrk = pcur; break; }
          if (lane == 0) recw[4 * pcur + ks] = (unsigned short)j;
          pcur = f_fl(rr);
        }
        int fl2 = 0;
        if (d2 != -1) {
          const int mlp2 = f_ml(reca[idbrk]);
          const u64m rd2 = reca[d2];
          const int mld = f_ml(rd2);
          if (mlp2 + 1 == mld) {
            fl2 = d2;
          } else {
            const int bbc = u++;
            const int drl = (int)(short)rla[d2];
            if (lane == 0) {
              reca[bbc] = (u64m)(unsigned short)f_tr(rd2, 0)
                        | ((u64m)(unsigned short)f_tr(rd2, 1) << 16)
                        | ((u64m)((unsigned)(rd2 >> 32) & 0xFFFFu) << 32)
                        | ((u64m)(unsigned)(mlp2 + 1) << 48);
              rla[bbc] = (unsigned short)drl;
              recw[4 * d2 + 2] = (unsigned short)bbc;   // fl[d2] = bbc
            }
            fl2 = bbc;
            int p3 = idbrk;
            for (;;) {
              if (p3 == -1) break;
              const u64m r3 = reca[p3];
              const int tv3 = f_tr(r3, ks);
              if (tv3 != d2) break;
              if (lane == 0) recw[4 * p3 + ks] = (unsigned short)bbc;
              p3 = f_fl(r3);
            }
          }
        }
        if (lane == 0)
          rech[2 * j + 1] = (unsigned)(fl2 & 0xFFFF) | ((unsigned)mlj << 16);
        // full propagation walk; rebuild lane chain while stamping
        int vp = j, ncs = 0;
        bool tr2 = false;
        for (;;) {
          if (vp == -1) break;
          if (ncs < 64) { if (lane == ncs) cid = vp; ++ncs; }
          else tr2 = true;
          if (lane == 0) rla[vp] = (unsigned short)i;
          vp = (int)(short)(rech[2 * vp + 1] & 0xFFFFu);
        }
        cval = (lane < ncs);
        trunc = tr2;
      }
      g = j; mlg = mlj;
    }
    // wave1: nothing in phase2.

    // next-step symbol (both waves, own stream)
    if (i + 1 < T) {
      const int in = i + 1;
      const unsigned bw = (unsigned)__builtin_amdgcn_readlane((int)bits, in >> 5);
      sym = (int)((bw >> (in & 31)) & 1u);
    }

    // drain wave0's LDS stores so wave1's next-phase1 reads see them; raw
    // barrier (no vmcnt drain: wave1's outr store stays in flight).
    asm volatile("s_waitcnt lgkmcnt(0)" ::: "memory");
    __builtin_amdgcn_s_barrier();   // ---- B: automaton post-i published ----
    asm volatile("" ::: "memory");
  }
}

// Fully parallel epilogue: vidx (u32, = r+1, 0 = no match) -> sign*e.
__global__ __launch_bounds__(256)
void samx_epilogue(const float* __restrict__ v,
                   const float* __restrict__ e,
                   unsigned* __restrict__ out,
                   int T, int C, int total) {
  const int idx = blockIdx.x * 256 + threadIdx.x;
  if (idx >= total) return;
  const unsigned vidx = out[idx];
  const int c = idx % C;
  const int bi = idx / C;
  const int b = bi / T;
  const float ev = e[c];
  float val = -ev;  // y=0
  if (vidx != 0u) {
    if (v[((size_t)b * (size_t)T + (size_t)vidx) * (size_t)C + (size_t)c] > 0.0f)
      val = ev;
  }
  out[idx] = __float_as_uint(val);
}

extern "C" void kernel_launch(void* const* d_in, const int* in_sizes, int n_in,
                              void* d_out, int out_size, void* d_ws, size_t ws_size,
                              hipStream_t stream) {
  const float* q = (const float*)d_in[0];
  const float* k = (const float*)d_in[1];
  const float* v = (const float*)d_in[2];
  const float* e = (const float*)d_in[3];

  const int C = in_sizes[3];
  const int T = TLEN;
  const int B = in_sizes[0] / (T * C);
  const int total = out_size;

  samx_main<<<dim3(B * C), dim3(128), 0, stream>>>(q, k, (unsigned*)d_out, T, C);
  samx_epilogue<<<dim3((total + 255) / 256), dim3(256), 0, stream>>>(
      v, e, (unsigned*)d_out, T, C, total);
}